// Round 6
// baseline (272.567 us; speedup 1.0000x reference)
//
#include <hip/hip_runtime.h>
#include <hip/hip_bf16.h>
#include <math.h>

#define B_ 64
#define N_ 64
#define C_ 8
#define F_ 256
#define K_ 2048    // C_*F_
#define NO_ 2048   // OC_*OF_
#define M_TOT 4160 // 64 (zx rows) + 4096 (zn rows)

typedef __attribute__((ext_vector_type(8))) short bf16x8;  // 8 bf16 = 4 VGPRs
typedef __attribute__((ext_vector_type(4))) float f32x4;

// ---------------------------------------------------------------------------
// Fused: s1[b], s2[b,n] reductions + Wc fp32->bf16 conversion (independent
// block ranges in one grid to save a serialized launch).
// blk < 4096: s2;  4096..4159: s1;  >=4160: wc convert.
__global__ __launch_bounds__(256) void sums_wc_k(const float* __restrict__ x,
        const float* __restrict__ nb, const float* __restrict__ W1,
        const float* __restrict__ W2, const float* __restrict__ Wc,
        float* __restrict__ s1, float* __restrict__ s2,
        __hip_bfloat16* __restrict__ Bbuf) {
    int blk = blockIdx.x;
    int f = threadIdx.x;
    if (blk >= B_ * N_ + B_) {
        int i = (blk - (B_ * N_ + B_)) * 1024 + f * 4;
        float4 v = *(const float4*)(Wc + i);
        Bbuf[i + 0] = __float2bfloat16(v.x);
        Bbuf[i + 1] = __float2bfloat16(v.y);
        Bbuf[i + 2] = __float2bfloat16(v.z);
        Bbuf[i + 3] = __float2bfloat16(v.w);
        return;
    }
    float val;
    if (blk < B_ * N_) {
        const float* base = nb + (size_t)blk * (C_ * F_);
        float wsum = 0.f;
        #pragma unroll
        for (int k = 0; k < C_; ++k) wsum += W2[k * F_ + f];
        float cs = 0.f;
        #pragma unroll
        for (int c = 0; c < C_; ++c) cs += base[c * F_ + f];
        val = cs * wsum;
    } else {
        int b = blk - B_ * N_;
        const float* base = x + (size_t)b * (C_ * F_);
        float wsum = 0.f;
        #pragma unroll
        for (int k = 0; k < C_; ++k) wsum += W1[k * F_ + f];
        float cs = 0.f;
        #pragma unroll
        for (int c = 0; c < C_; ++c) cs += base[c * F_ + f];
        val = cs * wsum;
    }
    #pragma unroll
    for (int off = 32; off > 0; off >>= 1) val += __shfl_down(val, off, 64);
    __shared__ float wred[4];
    int w = f >> 6;
    if ((f & 63) == 0) wred[w] = val;
    __syncthreads();
    if (f == 0) {
        float s = wred[0] + wred[1] + wred[2] + wred[3];
        if (blk < B_ * N_) s2[blk] = s;
        else s1[blk - B_ * N_] = s;
    }
}

// ---------------------------------------------------------------------------
// t[b,c,d] = s1[b] * sum_n nb[b,n,c,d] * s2[b,n]
__global__ __launch_bounds__(1024) void t_k(const float* __restrict__ nb,
        const float* __restrict__ s1, const float* __restrict__ s2,
        float* __restrict__ t) {
    int blk = blockIdx.x;  // b*C_ + c
    int b = blk / C_, c = blk % C_;
    int tid = threadIdx.x;
    int q = tid >> 8, d = tid & 255;
    const float* p = nb + ((size_t)(b * N_) * C_ + c) * F_ + d;
    const float* s2p = s2 + b * N_;
    float acc = 0.f;
    #pragma unroll
    for (int j = 0; j < 16; ++j) {
        int n = q * 16 + j;
        acc += p[(size_t)n * C_ * F_] * s2p[n];
    }
    __shared__ float part[4][F_];
    part[q][d] = acc;
    __syncthreads();
    if (tid < 256) {
        float s = part[0][d] + part[1][d] + part[2][d] + part[3][d];
        t[(size_t)blk * F_ + d] = s * s1[b];
    }
}

// ---------------------------------------------------------------------------
// rdenom[b,a,d] = 1 / (1e-7 + sum_c |sgnroot(x_a t_d + x_d t_a)|)
__global__ __launch_bounds__(256) void denom_k(const float* __restrict__ x,
        const float* __restrict__ t, float* __restrict__ rdenom) {
    int blk = blockIdx.x;  // b*F_ + a
    int b = blk >> 8, a = blk & 255;
    int d = threadIdx.x;
    float acc = 1e-7f;
    #pragma unroll
    for (int c = 0; c < C_; ++c) {
        size_t o = ((size_t)b * C_ + c) * F_;
        float xa = x[o + a], ta = t[o + a];
        float xd = x[o + d], td = t[o + d];
        float v = xa * td + xd * ta;
        float r = __builtin_amdgcn_sqrtf(fmaxf(fabsf(v), 1e-8f));
        acc += (v != 0.f) ? r : 0.f;
    }
    rdenom[(size_t)blk * F_ + d] = __builtin_amdgcn_rcpf(acc);
}

__device__ __forceinline__ float sgnroot_dev(float v) {
    float r = __builtin_amdgcn_sqrtf(fmaxf(fabsf(v), 1e-8f));
    return (v > 0.f) ? r : ((v < 0.f) ? -r : 0.f);
}

// ---------------------------------------------------------------------------
// Fused zx+zn via MFMA. One block per (b,c). LDS rows (stride ZNX_PAD=264):
//   rows 0..63 = nb[b,:,c,:], row 64 = x[b,c,:], rows 65..79 = 0  (bf16)
#define ZNX_PAD 264  // row STRIDE in bf16: 256 data + 8 pad
__global__ __launch_bounds__(256) void znx_k(const float* __restrict__ x,
        const float* __restrict__ t, const float* __restrict__ rdenom,
        const float* __restrict__ nb, __hip_bfloat16* __restrict__ Abuf) {
    int bc = blockIdx.x;
    int b = bc >> 3, c = bc & 7;
    int tid = threadIdx.x;
    int wave = tid >> 6, lane = tid & 63;
    __shared__ float xs[F_], ts[F_];
    __shared__ __hip_bfloat16 nbB[80 * ZNX_PAD];  // 42240 B

    xs[tid] = x[(size_t)bc * F_ + tid];
    ts[tid] = t[(size_t)bc * F_ + tid];
    {
        int r = tid >> 2, cs0 = (tid & 3) * 64;
        const float* src = nb + (((size_t)(b * N_ + r)) * C_ + c) * F_ + cs0;
        __hip_bfloat16* dst = nbB + r * ZNX_PAD + cs0;
        #pragma unroll
        for (int j = 0; j < 64; j += 4) {
            float4 v = *(const float4*)(src + j);
            dst[j + 0] = __float2bfloat16(v.x);
            dst[j + 1] = __float2bfloat16(v.y);
            dst[j + 2] = __float2bfloat16(v.z);
            dst[j + 3] = __float2bfloat16(v.w);
        }
    }
    if (tid < 64) {
        float4 v = *(const float4*)(x + (size_t)bc * F_ + tid * 4);
        __hip_bfloat16* dst = nbB + 64 * ZNX_PAD + tid * 4;
        dst[0] = __float2bfloat16(v.x);
        dst[1] = __float2bfloat16(v.y);
        dst[2] = __float2bfloat16(v.z);
        dst[3] = __float2bfloat16(v.w);
    }
    {
        __hip_bfloat16 z = __float2bfloat16(0.f);
        #pragma unroll
        for (int j = 0; j < 16; ++j) {
            int o = 65 * ZNX_PAD + tid * 16 + j;
            if (o < 80 * ZNX_PAD) nbB[o] = z;
        }
    }
    __syncthreads();

    const int aq = lane & 15;
    const int dq = lane >> 4;
    #pragma unroll
    for (int atile = 0; atile < 4; ++atile) {
        int a = wave * 64 + atile * 16 + aq;
        float xa = xs[a], ta = ts[a];
        const float* drow = rdenom + ((size_t)b * F_ + a) * F_;
        f32x4 acc[5] = {};
        #pragma unroll
        for (int kc = 0; kc < 8; ++kc) {
            int d0 = kc * 32 + dq * 8;
            float4 xv0 = *(const float4*)(xs + d0);
            float4 xv1 = *(const float4*)(xs + d0 + 4);
            float4 tv0 = *(const float4*)(ts + d0);
            float4 tv1 = *(const float4*)(ts + d0 + 4);
            float4 dn0 = *(const float4*)(drow + d0);
            float4 dn1 = *(const float4*)(drow + d0 + 4);
            float xv[8] = {xv0.x, xv0.y, xv0.z, xv0.w, xv1.x, xv1.y, xv1.z, xv1.w};
            float tv[8] = {tv0.x, tv0.y, tv0.z, tv0.w, tv1.x, tv1.y, tv1.z, tv1.w};
            float dn[8] = {dn0.x, dn0.y, dn0.z, dn0.w, dn1.x, dn1.y, dn1.z, dn1.w};
            union { bf16x8 v; __hip_bfloat16 h[8]; } bu;
            #pragma unroll
            for (int j = 0; j < 8; ++j) {
                float g = sgnroot_dev(xa * tv[j] + xv[j] * ta);
                bu.h[j] = __float2bfloat16(g * dn[j]);   // dn = 1/denom
            }
            #pragma unroll
            for (int mt = 0; mt < 5; ++mt) {
                bf16x8 af = *(const bf16x8*)(nbB + (mt * 16 + aq) * ZNX_PAD
                                             + kc * 32 + dq * 8);
                acc[mt] = __builtin_amdgcn_mfma_f32_16x16x32_bf16(
                    af, bu.v, acc[mt], 0, 0, 0);
            }
        }
        int colA = c * F_ + a;
        #pragma unroll
        for (int mt = 0; mt < 4; ++mt) {
            int row = 64 + b * N_ + mt * 16 + dq * 4;
            #pragma unroll
            for (int i = 0; i < 4; ++i)
                Abuf[(size_t)(row + i) * K_ + colA] = __float2bfloat16(acc[mt][i]);
        }
        if (dq == 0)
            Abuf[(size_t)b * K_ + colA] = __float2bfloat16(acc[4][0]);
    }
}

// ---------------------------------------------------------------------------
// C[M_TOT, 2048] = A[M_TOT, 2048] @ B[2048, 2048]^T, bf16 in, fp32 out.
// K-MAJOR LDS SLABS: slab kc8 (8 k-values) x 128 rows, addr = kc8*2048+row*16.
// Fragment read bank-start = 4*aq%32 -> conflict-free per 8-lane phase
// (old row-major layout was 4-way conflicted: 4.3M SQ_LDS_BANK_CONFLICT).
// global_load_lds lane-contiguity holds: lds chunk id == thread id.
__global__ __launch_bounds__(256) void gemm_bf16_k(
        const __hip_bfloat16* __restrict__ A,
        const __hip_bfloat16* __restrict__ Bm,
        float* __restrict__ Cm) {
    __shared__ char ldsA[8192] __attribute__((aligned(16)));
    __shared__ char ldsB[8192] __attribute__((aligned(16)));
    const int t = threadIdx.x;
    const int wave = t >> 6;
    const int lane = t & 63;
    const int col0 = blockIdx.x * 128;
    const int row0 = blockIdx.y * 128;
    const int wrow0 = (wave & 1) * 64;
    const int wcol0 = (wave >> 1) * 64;
    const int aq = lane & 15;
    const int dq = lane >> 4;

    // staging: issue0 covers slabs 0..1 (k 0..15), issue1 slabs 2..3 (k 16..31)
    // wave w: rows (w&1)*64 + lane, slab base w>>1
    const int srow = (wave & 1) * 64 + lane;
    const int slab = wave >> 1;                 // 0 or 1
    const int grA = min(row0 + srow, M_TOT - 1);
    const int gcB = col0 + srow;
    const __hip_bfloat16* gA = A + (size_t)grA * K_ + slab * 8;
    const __hip_bfloat16* gB = Bm + (size_t)gcB * K_ + slab * 8;
    char* lA0 = ldsA + wave * 1024;
    char* lA1 = ldsA + 4096 + wave * 1024;
    char* lB0 = ldsB + wave * 1024;
    char* lB1 = ldsB + 4096 + wave * 1024;

    f32x4 acc[4][4] = {};

    for (int k0 = 0; k0 < K_; k0 += 32) {
        __syncthreads();
        __builtin_amdgcn_global_load_lds(
            (const __attribute__((address_space(1))) void*)(gA + k0),
            (__attribute__((address_space(3))) void*)lA0, 16, 0, 0);
        __builtin_amdgcn_global_load_lds(
            (const __attribute__((address_space(1))) void*)(gA + k0 + 16),
            (__attribute__((address_space(3))) void*)lA1, 16, 0, 0);
        __builtin_amdgcn_global_load_lds(
            (const __attribute__((address_space(1))) void*)(gB + k0),
            (__attribute__((address_space(3))) void*)lB0, 16, 0, 0);
        __builtin_amdgcn_global_load_lds(
            (const __attribute__((address_space(1))) void*)(gB + k0 + 16),
            (__attribute__((address_space(3))) void*)lB1, 16, 0, 0);
        __syncthreads();

        bf16x8 af[4], bf[4];
        #pragma unroll
        for (int rb = 0; rb < 4; ++rb)
            af[rb] = *(const bf16x8*)(ldsA + dq * 2048
                                      + (wrow0 + rb * 16 + aq) * 16);
        #pragma unroll
        for (int cb = 0; cb < 4; ++cb)
            bf[cb] = *(const bf16x8*)(ldsB + dq * 2048
                                      + (wcol0 + cb * 16 + aq) * 16);
        #pragma unroll
        for (int rb = 0; rb < 4; ++rb)
            #pragma unroll
            for (int cb = 0; cb < 4; ++cb)
                acc[rb][cb] = __builtin_amdgcn_mfma_f32_16x16x32_bf16(
                    af[rb], bf[cb], acc[rb][cb], 0, 0, 0);
    }

    #pragma unroll
    for (int rb = 0; rb < 4; ++rb) {
        int rowbase = row0 + wrow0 + rb * 16 + (lane >> 4) * 4;
        #pragma unroll
        for (int cb = 0; cb < 4; ++cb) {
            int col = col0 + wcol0 + cb * 16 + (lane & 15);
            #pragma unroll
            for (int i = 0; i < 4; ++i) {
                int row = rowbase + i;
                if (row < M_TOT)
                    Cm[(size_t)row * NO_ + col] = acc[rb][cb][i];
            }
        }
    }
}

// ---------------------------------------------------------------------------
extern "C" void kernel_launch(void* const* d_in, const int* in_sizes, int n_in,
                              void* d_out, int out_size, void* d_ws, size_t ws_size,
                              hipStream_t stream) {
    const float* x  = (const float*)d_in[0];
    const float* nb = (const float*)d_in[1];
    const float* W1 = (const float*)d_in[2];
    const float* W2 = (const float*)d_in[3];
    const float* Wc = (const float*)d_in[4];
    float* out = (float*)d_out;
    float* ws = (float*)d_ws;

    float* s1    = ws;            // 64 f
    float* s2    = ws + 64;       // 4096 f
    float* t     = ws + 4160;     // 131072 f
    float* rden  = ws + 135232;   // 4194304 f (B*F*F), stores 1/denom
    __hip_bfloat16* Abuf = (__hip_bfloat16*)(ws + 4329536);   // 4160*2048 bf16
    __hip_bfloat16* Bbuf = Abuf + (size_t)M_TOT * K_;         // 2048*2048 bf16

    hipLaunchKernelGGL(sums_wc_k, dim3(B_ * N_ + B_ + (K_ * NO_) / 1024),
                       dim3(256), 0, stream, x, nb, W1, W2, Wc, s1, s2, Bbuf);
    hipLaunchKernelGGL(t_k, dim3(B_ * C_), dim3(1024), 0, stream, nb, s1, s2, t);
    hipLaunchKernelGGL(denom_k, dim3(B_ * F_), dim3(256), 0, stream, x, t, rden);
    hipLaunchKernelGGL(znx_k, dim3(B_ * C_), dim3(256), 0, stream,
                       x, t, rden, nb, Abuf);
    hipLaunchKernelGGL(gemm_bf16_k, dim3(16, 33), dim3(256), 0, stream,
                       Abuf, Bbuf, out);
}

// Round 7
// 232.688 us; speedup vs baseline: 1.1714x; 1.1714x over previous
//
#include <hip/hip_runtime.h>
#include <hip/hip_bf16.h>
#include <math.h>

#define B_ 64
#define N_ 64
#define C_ 8
#define F_ 256
#define K_ 2048    // C_*F_
#define NO_ 2048   // OC_*OF_
#define M_TOT 4160 // 64 (zx rows) + 4096 (zn rows)

typedef __attribute__((ext_vector_type(8))) short bf16x8;  // 8 bf16 = 4 VGPRs
typedef __attribute__((ext_vector_type(4))) float f32x4;

// ---------------------------------------------------------------------------
// Fused: s1[b], s2[b,n] reductions + Wc fp32->bf16 conversion.
// blk < 4096: s2;  4096..4159: s1;  >=4160: wc convert.
__global__ __launch_bounds__(256) void sums_wc_k(const float* __restrict__ x,
        const float* __restrict__ nb, const float* __restrict__ W1,
        const float* __restrict__ W2, const float* __restrict__ Wc,
        float* __restrict__ s1, float* __restrict__ s2,
        __hip_bfloat16* __restrict__ Bbuf) {
    int blk = blockIdx.x;
    int f = threadIdx.x;
    if (blk >= B_ * N_ + B_) {
        int i = (blk - (B_ * N_ + B_)) * 1024 + f * 4;
        float4 v = *(const float4*)(Wc + i);
        Bbuf[i + 0] = __float2bfloat16(v.x);
        Bbuf[i + 1] = __float2bfloat16(v.y);
        Bbuf[i + 2] = __float2bfloat16(v.z);
        Bbuf[i + 3] = __float2bfloat16(v.w);
        return;
    }
    float val;
    if (blk < B_ * N_) {
        const float* base = nb + (size_t)blk * (C_ * F_);
        float wsum = 0.f;
        #pragma unroll
        for (int k = 0; k < C_; ++k) wsum += W2[k * F_ + f];
        float cs = 0.f;
        #pragma unroll
        for (int c = 0; c < C_; ++c) cs += base[c * F_ + f];
        val = cs * wsum;
    } else {
        int b = blk - B_ * N_;
        const float* base = x + (size_t)b * (C_ * F_);
        float wsum = 0.f;
        #pragma unroll
        for (int k = 0; k < C_; ++k) wsum += W1[k * F_ + f];
        float cs = 0.f;
        #pragma unroll
        for (int c = 0; c < C_; ++c) cs += base[c * F_ + f];
        val = cs * wsum;
    }
    #pragma unroll
    for (int off = 32; off > 0; off >>= 1) val += __shfl_down(val, off, 64);
    __shared__ float wred[4];
    int w = f >> 6;
    if ((f & 63) == 0) wred[w] = val;
    __syncthreads();
    if (f == 0) {
        float s = wred[0] + wred[1] + wred[2] + wred[3];
        if (blk < B_ * N_) s2[blk] = s;
        else s1[blk - B_ * N_] = s;
    }
}

// ---------------------------------------------------------------------------
// t[b,c,d] = s1[b] * sum_n nb[b,n,c,d] * s2[b,n]
__global__ __launch_bounds__(1024) void t_k(const float* __restrict__ nb,
        const float* __restrict__ s1, const float* __restrict__ s2,
        float* __restrict__ t) {
    int blk = blockIdx.x;  // b*C_ + c
    int b = blk / C_, c = blk % C_;
    int tid = threadIdx.x;
    int q = tid >> 8, d = tid & 255;
    const float* p = nb + ((size_t)(b * N_) * C_ + c) * F_ + d;
    const float* s2p = s2 + b * N_;
    float acc = 0.f;
    #pragma unroll
    for (int j = 0; j < 16; ++j) {
        int n = q * 16 + j;
        acc += p[(size_t)n * C_ * F_] * s2p[n];
    }
    __shared__ float part[4][F_];
    part[q][d] = acc;
    __syncthreads();
    if (tid < 256) {
        float s = part[0][d] + part[1][d] + part[2][d] + part[3][d];
        t[(size_t)blk * F_ + d] = s * s1[b];
    }
}

// ---------------------------------------------------------------------------
// rdenom[b,a,d] = 1 / (1e-7 + sum_c |sgnroot(x_a t_d + x_d t_a)|)
__global__ __launch_bounds__(256) void denom_k(const float* __restrict__ x,
        const float* __restrict__ t, float* __restrict__ rdenom) {
    int blk = blockIdx.x;  // b*F_ + a
    int b = blk >> 8, a = blk & 255;
    int d = threadIdx.x;
    float acc = 1e-7f;
    #pragma unroll
    for (int c = 0; c < C_; ++c) {
        size_t o = ((size_t)b * C_ + c) * F_;
        float xa = x[o + a], ta = t[o + a];
        float xd = x[o + d], td = t[o + d];
        float v = xa * td + xd * ta;
        float r = __builtin_amdgcn_sqrtf(fmaxf(fabsf(v), 1e-8f));
        acc += (v != 0.f) ? r : 0.f;
    }
    rdenom[(size_t)blk * F_ + d] = __builtin_amdgcn_rcpf(acc);
}

__device__ __forceinline__ float sgnroot_dev(float v) {
    float r = __builtin_amdgcn_sqrtf(fmaxf(fabsf(v), 1e-8f));
    return (v > 0.f) ? r : ((v < 0.f) ? -r : 0.f);
}

// ---------------------------------------------------------------------------
// Fused zx+zn via MFMA. One block per (b,c).
#define ZNX_PAD 264  // row STRIDE in bf16: 256 data + 8 pad
__global__ __launch_bounds__(256) void znx_k(const float* __restrict__ x,
        const float* __restrict__ t, const float* __restrict__ rdenom,
        const float* __restrict__ nb, __hip_bfloat16* __restrict__ Abuf) {
    int bc = blockIdx.x;
    int b = bc >> 3, c = bc & 7;
    int tid = threadIdx.x;
    int wave = tid >> 6, lane = tid & 63;
    __shared__ float xs[F_], ts[F_];
    __shared__ __hip_bfloat16 nbB[80 * ZNX_PAD];  // 42240 B

    xs[tid] = x[(size_t)bc * F_ + tid];
    ts[tid] = t[(size_t)bc * F_ + tid];
    {
        int r = tid >> 2, cs0 = (tid & 3) * 64;
        const float* src = nb + (((size_t)(b * N_ + r)) * C_ + c) * F_ + cs0;
        __hip_bfloat16* dst = nbB + r * ZNX_PAD + cs0;
        #pragma unroll
        for (int j = 0; j < 64; j += 4) {
            float4 v = *(const float4*)(src + j);
            dst[j + 0] = __float2bfloat16(v.x);
            dst[j + 1] = __float2bfloat16(v.y);
            dst[j + 2] = __float2bfloat16(v.z);
            dst[j + 3] = __float2bfloat16(v.w);
        }
    }
    if (tid < 64) {
        float4 v = *(const float4*)(x + (size_t)bc * F_ + tid * 4);
        __hip_bfloat16* dst = nbB + 64 * ZNX_PAD + tid * 4;
        dst[0] = __float2bfloat16(v.x);
        dst[1] = __float2bfloat16(v.y);
        dst[2] = __float2bfloat16(v.z);
        dst[3] = __float2bfloat16(v.w);
    }
    {
        __hip_bfloat16 z = __float2bfloat16(0.f);
        #pragma unroll
        for (int j = 0; j < 16; ++j) {
            int o = 65 * ZNX_PAD + tid * 16 + j;
            if (o < 80 * ZNX_PAD) nbB[o] = z;
        }
    }
    __syncthreads();

    const int aq = lane & 15;
    const int dq = lane >> 4;
    #pragma unroll
    for (int atile = 0; atile < 4; ++atile) {
        int a = wave * 64 + atile * 16 + aq;
        float xa = xs[a], ta = ts[a];
        const float* drow = rdenom + ((size_t)b * F_ + a) * F_;
        f32x4 acc[5] = {};
        #pragma unroll
        for (int kc = 0; kc < 8; ++kc) {
            int d0 = kc * 32 + dq * 8;
            float4 xv0 = *(const float4*)(xs + d0);
            float4 xv1 = *(const float4*)(xs + d0 + 4);
            float4 tv0 = *(const float4*)(ts + d0);
            float4 tv1 = *(const float4*)(ts + d0 + 4);
            float4 dn0 = *(const float4*)(drow + d0);
            float4 dn1 = *(const float4*)(drow + d0 + 4);
            float xv[8] = {xv0.x, xv0.y, xv0.z, xv0.w, xv1.x, xv1.y, xv1.z, xv1.w};
            float tv[8] = {tv0.x, tv0.y, tv0.z, tv0.w, tv1.x, tv1.y, tv1.z, tv1.w};
            float dn[8] = {dn0.x, dn0.y, dn0.z, dn0.w, dn1.x, dn1.y, dn1.z, dn1.w};
            union { bf16x8 v; __hip_bfloat16 h[8]; } bu;
            #pragma unroll
            for (int j = 0; j < 8; ++j) {
                float g = sgnroot_dev(xa * tv[j] + xv[j] * ta);
                bu.h[j] = __float2bfloat16(g * dn[j]);   // dn = 1/denom
            }
            #pragma unroll
            for (int mt = 0; mt < 5; ++mt) {
                bf16x8 af = *(const bf16x8*)(nbB + (mt * 16 + aq) * ZNX_PAD
                                             + kc * 32 + dq * 8);
                acc[mt] = __builtin_amdgcn_mfma_f32_16x16x32_bf16(
                    af, bu.v, acc[mt], 0, 0, 0);
            }
        }
        int colA = c * F_ + a;
        #pragma unroll
        for (int mt = 0; mt < 4; ++mt) {
            int row = 64 + b * N_ + mt * 16 + dq * 4;
            #pragma unroll
            for (int i = 0; i < 4; ++i)
                Abuf[(size_t)(row + i) * K_ + colA] = __float2bfloat16(acc[mt][i]);
        }
        if (dq == 0)
            Abuf[(size_t)b * K_ + colA] = __float2bfloat16(acc[4][0]);
    }
}

// ---------------------------------------------------------------------------
// C[M_TOT, 2048] = A[M_TOT, 2048] @ B[2048, 2048]^T, bf16 in, fp32 out.
// SWIZZLED row-major LDS: position p(row,kc) = (kc + ((row>>1)&3)) & 3.
//  - staging: lane t loads kc = ((t&3) - ((t>>3)&3)) & 3 of row t>>2
//    -> 4 lanes still cover one row's 64B window (coalesced, as R5)
//  - fragment read: offset = row*64 + ((dq + (aq>>1))&3)*16
//    -> bank-group (4*row+p) mod 8 spans all 8 groups per 8-lane phase
//    (conflict-free; R5's layout was 4-way conflicted, R6's staging was
//     uncoalesced 16B-scatter -- this gets both properties).
__global__ __launch_bounds__(256) void gemm_bf16_k(
        const __hip_bfloat16* __restrict__ A,
        const __hip_bfloat16* __restrict__ Bm,
        float* __restrict__ Cm) {
    __shared__ char ldsA[8192] __attribute__((aligned(16)));
    __shared__ char ldsB[8192] __attribute__((aligned(16)));
    const int t = threadIdx.x;
    const int wave = t >> 6;
    const int lane = t & 63;
    const int col0 = blockIdx.x * 128;
    const int row0 = blockIdx.y * 128;
    const int wrow0 = (wave & 1) * 64;
    const int wcol0 = (wave >> 1) * 64;
    const int aq = lane & 15;
    const int dq = lane >> 4;

    const int rA0 = t >> 2;                               // row 0..63 (issue 0)
    const int kcs = ((t & 3) - ((t >> 3) & 3)) & 3;       // swizzled k-chunk
    const int kc = kcs * 8;                               // element offset
    const int grA0 = min(row0 + rA0, M_TOT - 1);
    const int grA1 = min(row0 + rA0 + 64, M_TOT - 1);
    const int gcB0 = col0 + rA0;
    const int gcB1 = col0 + rA0 + 64;
    char* lA0 = ldsA + wave * 1024;
    char* lA1 = ldsA + 4096 + wave * 1024;
    char* lB0 = ldsB + wave * 1024;
    char* lB1 = ldsB + 4096 + wave * 1024;

    const int swz = ((dq + (aq >> 1)) & 3) * 16;          // read-side position

    f32x4 acc[4][4] = {};

    for (int k0 = 0; k0 < K_; k0 += 32) {
        __syncthreads();
        __builtin_amdgcn_global_load_lds(
            (const __attribute__((address_space(1))) void*)(A + (size_t)grA0 * K_ + k0 + kc),
            (__attribute__((address_space(3))) void*)lA0, 16, 0, 0);
        __builtin_amdgcn_global_load_lds(
            (const __attribute__((address_space(1))) void*)(A + (size_t)grA1 * K_ + k0 + kc),
            (__attribute__((address_space(3))) void*)lA1, 16, 0, 0);
        __builtin_amdgcn_global_load_lds(
            (const __attribute__((address_space(1))) void*)(Bm + (size_t)gcB0 * K_ + k0 + kc),
            (__attribute__((address_space(3))) void*)lB0, 16, 0, 0);
        __builtin_amdgcn_global_load_lds(
            (const __attribute__((address_space(1))) void*)(Bm + (size_t)gcB1 * K_ + k0 + kc),
            (__attribute__((address_space(3))) void*)lB1, 16, 0, 0);
        __syncthreads();

        bf16x8 af[4], bf[4];
        #pragma unroll
        for (int rb = 0; rb < 4; ++rb)
            af[rb] = *(const bf16x8*)(ldsA + (wrow0 + rb * 16 + aq) * 64 + swz);
        #pragma unroll
        for (int cb = 0; cb < 4; ++cb)
            bf[cb] = *(const bf16x8*)(ldsB + (wcol0 + cb * 16 + aq) * 64 + swz);
        #pragma unroll
        for (int rb = 0; rb < 4; ++rb)
            #pragma unroll
            for (int cb = 0; cb < 4; ++cb)
                acc[rb][cb] = __builtin_amdgcn_mfma_f32_16x16x32_bf16(
                    af[rb], bf[cb], acc[rb][cb], 0, 0, 0);
    }

    #pragma unroll
    for (int rb = 0; rb < 4; ++rb) {
        int rowbase = row0 + wrow0 + rb * 16 + (lane >> 4) * 4;
        #pragma unroll
        for (int cb = 0; cb < 4; ++cb) {
            int col = col0 + wcol0 + cb * 16 + (lane & 15);
            #pragma unroll
            for (int i = 0; i < 4; ++i) {
                int row = rowbase + i;
                if (row < M_TOT)
                    Cm[(size_t)row * NO_ + col] = acc[rb][cb][i];
            }
        }
    }
}

// ---------------------------------------------------------------------------
extern "C" void kernel_launch(void* const* d_in, const int* in_sizes, int n_in,
                              void* d_out, int out_size, void* d_ws, size_t ws_size,
                              hipStream_t stream) {
    const float* x  = (const float*)d_in[0];
    const float* nb = (const float*)d_in[1];
    const float* W1 = (const float*)d_in[2];
    const float* W2 = (const float*)d_in[3];
    const float* Wc = (const float*)d_in[4];
    float* out = (float*)d_out;
    float* ws = (float*)d_ws;

    float* s1    = ws;            // 64 f
    float* s2    = ws + 64;       // 4096 f
    float* t     = ws + 4160;     // 131072 f
    float* rden  = ws + 135232;   // 4194304 f (B*F*F), stores 1/denom
    __hip_bfloat16* Abuf = (__hip_bfloat16*)(ws + 4329536);   // 4160*2048 bf16
    __hip_bfloat16* Bbuf = Abuf + (size_t)M_TOT * K_;         // 2048*2048 bf16

    hipLaunchKernelGGL(sums_wc_k, dim3(B_ * N_ + B_ + (K_ * NO_) / 1024),
                       dim3(256), 0, stream, x, nb, W1, W2, Wc, s1, s2, Bbuf);
    hipLaunchKernelGGL(t_k, dim3(B_ * C_), dim3(1024), 0, stream, nb, s1, s2, t);
    hipLaunchKernelGGL(denom_k, dim3(B_ * F_), dim3(256), 0, stream, x, t, rden);
    hipLaunchKernelGGL(znx_k, dim3(B_ * C_), dim3(256), 0, stream,
                       x, t, rden, nb, Abuf);
    hipLaunchKernelGGL(gemm_bf16_k, dim3(16, 33), dim3(256), 0, stream,
                       Abuf, Bbuf, out);
}